// Round 1
// baseline (2949.336 us; speedup 1.0000x reference)
//
#include <hip/hip_runtime.h>
#include <hip/hip_bf16.h>
#include <math.h>

typedef unsigned short u16;
typedef __bf16 bf16x8 __attribute__((ext_vector_type(8)));
typedef float f32x4 __attribute__((ext_vector_type(4)));
typedef u16 u16x8 __attribute__((ext_vector_type(8)));
typedef u16 u16x4 __attribute__((ext_vector_type(4)));

#define DEVI static __device__ __forceinline__

DEVI u16 f2bf(float f) {
  union { float f; unsigned u; } v; v.f = f;
  unsigned r = v.u + 0x7fffu + ((v.u >> 16) & 1u);
  return (u16)(r >> 16);
}
DEVI float bf2f(u16 b) {
  union { unsigned u; float f; } v; v.u = ((unsigned)b) << 16;
  return v.f;
}

// async global->LDS, 16B per lane; LDS dest = wave-uniform base + lane*16
#define GLDS16(g, l) __builtin_amdgcn_global_load_lds( \
    (const __attribute__((address_space(1))) void*)(g), \
    (__attribute__((address_space(3))) void*)(l), 16, 0, 0)

// ---------------------------------------------------------------- rmsnorm row=1024
template<int OUTF32>
__global__ __launch_bounds__(256) void rmsnorm1024(
    const float* __restrict__ in, const float* __restrict__ sc, void* __restrict__ out)
{
  const int row = blockIdx.x, tid = threadIdx.x;
  const float4 v = *(const float4*)&in[(size_t)row * 1024 + tid * 4];
  float ss = v.x * v.x + v.y * v.y + v.z * v.z + v.w * v.w;
#pragma unroll
  for (int m = 1; m < 64; m <<= 1) ss += __shfl_xor(ss, m);
  __shared__ float ws4[4];
  if ((tid & 63) == 0) ws4[tid >> 6] = ss;
  __syncthreads();
  const float tot = ws4[0] + ws4[1] + ws4[2] + ws4[3];
  const float rs = rsqrtf(tot * (1.f / 1024.f) + 1e-6f);
  const float4 s4 = *(const float4*)&sc[tid * 4];
  if (OUTF32) {
    float4 o; o.x = v.x * rs * s4.x; o.y = v.y * rs * s4.y; o.z = v.z * rs * s4.z; o.w = v.w * rs * s4.w;
    *(float4*)((float*)out + (size_t)row * 1024 + tid * 4) = o;
  } else {
    u16x4 o; o[0] = f2bf(v.x * rs * s4.x); o[1] = f2bf(v.y * rs * s4.y);
    o[2] = f2bf(v.z * rs * s4.z); o[3] = f2bf(v.w * rs * s4.w);
    *(u16x4*)((u16*)out + (size_t)row * 1024 + tid * 4) = o;
  }
}

// ---------------------------------------------------------------- misc small kernels
__global__ __launch_bounds__(256) void lat_init(
    const float* __restrict__ latents, float* __restrict__ lat)
{
  const int row = blockIdx.x;           // 0..2047 = b*64+q
  const int q = row & 63;
  *(float4*)&lat[(size_t)row * 1024 + threadIdx.x * 4] =
      *(const float4*)&latents[(size_t)q * 1024 + threadIdx.x * 4];
}

__global__ __launch_bounds__(256) void bias_init(
    const int* __restrict__ mask, float* __restrict__ bias, int n)
{
  const int i = blockIdx.x * 256 + threadIdx.x;
  if (i < n) bias[i] = mask[i] > 0 ? 0.f : -1e10f;
}

// per-layer weight pack: f32 [K][N] -> bf16 [N][K] (B^T layout for GEMM)
__global__ __launch_bounds__(256) void transpose_weights(
    const float* __restrict__ wq, const float* __restrict__ wk,
    const float* __restrict__ wv, const float* __restrict__ wo,
    const float* __restrict__ wi, const float* __restrict__ wom,
    u16* __restrict__ wqT, u16* __restrict__ wkT, u16* __restrict__ wvT,
    u16* __restrict__ woT, u16* __restrict__ wiT, u16* __restrict__ womT)
{
  int t = blockIdx.x;
  const float* src; u16* dst; int N, K;
  if (t < 1024) {
    const int m = t >> 8; t &= 255;
    src = m == 0 ? wq : m == 1 ? wk : m == 2 ? wv : wo;
    dst = m == 0 ? wqT : m == 1 ? wkT : m == 2 ? wvT : woT;
    N = 1024; K = 1024;
  } else if (t < 2048) { src = wi; dst = wiT; N = 4096; K = 1024; t -= 1024; }
  else { src = wom; dst = womT; N = 1024; K = 4096; t -= 2048; }
  const int tn = N >> 6;
  const int k0 = (t / tn) << 6, n0 = (t % tn) << 6;
  __shared__ float tile[64][65];
  const int tid = threadIdx.x;
  const int r = tid >> 2, c4 = tid & 3;
  const float* s = src + (size_t)(k0 + r) * N + n0 + c4 * 16;
#pragma unroll
  for (int i = 0; i < 4; ++i) {
    const float4 v = *(const float4*)(s + i * 4);
    tile[r][c4 * 16 + i * 4 + 0] = v.x; tile[r][c4 * 16 + i * 4 + 1] = v.y;
    tile[r][c4 * 16 + i * 4 + 2] = v.z; tile[r][c4 * 16 + i * 4 + 3] = v.w;
  }
  __syncthreads();
  u16x8 o0, o1;
#pragma unroll
  for (int i = 0; i < 8; ++i) o0[i] = f2bf(tile[c4 * 16 + i][r]);
#pragma unroll
  for (int i = 0; i < 8; ++i) o1[i] = f2bf(tile[c4 * 16 + 8 + i][r]);
  u16* d = dst + (size_t)(n0 + r) * K + k0 + c4 * 16;
  *(u16x8*)d = o0;
  *(u16x8*)(d + 8) = o1;
}

// in-place per-head RMS norm on head-major bf16 [G][64]; 16 threads per group
__global__ __launch_bounds__(256) void qknorm2(
    u16* __restrict__ q, const float* __restrict__ qs,
    u16* __restrict__ k, const float* __restrict__ ks, int qgroups)
{
  int g = blockIdx.x * 16 + (threadIdx.x >> 4);
  const int e = (threadIdx.x & 15) * 4;
  u16* d; const float* sc; float mult;
  if (g < qgroups) { d = q; sc = qs; mult = 0.125f; }   // * HD^-0.5
  else { d = k; sc = ks; mult = 1.f; g -= qgroups; }
  u16x4 raw = *(u16x4*)&d[(size_t)g * 64 + e];
  const float x0 = bf2f(raw[0]), x1 = bf2f(raw[1]), x2 = bf2f(raw[2]), x3 = bf2f(raw[3]);
  float ss = x0 * x0 + x1 * x1 + x2 * x2 + x3 * x3;
  ss += __shfl_xor(ss, 1); ss += __shfl_xor(ss, 2);
  ss += __shfl_xor(ss, 4); ss += __shfl_xor(ss, 8);
  const float rs = rsqrtf(ss * (1.f / 64.f) + 1e-6f) * mult;
  raw[0] = f2bf(x0 * rs * sc[e]);     raw[1] = f2bf(x1 * rs * sc[e + 1]);
  raw[2] = f2bf(x2 * rs * sc[e + 2]); raw[3] = f2bf(x3 * rs * sc[e + 3]);
  *(u16x4*)&d[(size_t)g * 64 + e] = raw;
}

// V [bh][S][64] -> V^T [bh][64][S]
__global__ __launch_bounds__(256) void vtrans(
    const u16* __restrict__ v, u16* __restrict__ vt, int S)
{
  const int nt = S >> 6;
  const int bh = blockIdx.x / nt, s0 = (blockIdx.x % nt) << 6;
  const u16* src = v + (size_t)bh * S * 64 + (size_t)s0 * 64;
  u16* dst = vt + (size_t)bh * 64 * S + s0;
  __shared__ u16 tile[64][72];
  const int tid = threadIdx.x;
  const int r = tid >> 2, c4 = tid & 3;
  *(u16x8*)&tile[r][c4 * 16] = *(const u16x8*)&src[(size_t)r * 64 + c4 * 16];
  *(u16x8*)&tile[r][c4 * 16 + 8] = *(const u16x8*)&src[(size_t)r * 64 + c4 * 16 + 8];
  __syncthreads();
  u16x8 o0, o1;
#pragma unroll
  for (int i = 0; i < 8; ++i) o0[i] = tile[c4 * 16 + i][r];
#pragma unroll
  for (int i = 0; i < 8; ++i) o1[i] = tile[c4 * 16 + 8 + i][r];
  u16* d = dst + (size_t)r * S + c4 * 16;
  *(u16x8*)d = o0;
  *(u16x8*)(d + 8) = o1;
}

// ---------------------------------------------------------------- GEMM (m97 structure)
// C[M,N] = A(bf16 [M][K]) @ W, with Bt = W^T bf16 [N][K].
enum { EPI_HEAD = 0, EPI_RESID = 1, EPI_GELU = 2 };

template<int EPI>
__global__ __launch_bounds__(256) void gemm_bf16(
    const u16* __restrict__ A, const u16* __restrict__ Bt,
    void* __restrict__ out, const float* __restrict__ resid,
    int M, int N, int K, int Rb)
{
  __shared__ u16 Alds[128 * 32];
  __shared__ u16 Blds[128 * 32];
  const int tiles_n = N >> 7;
  const int m0 = (blockIdx.x / tiles_n) << 7;
  const int n0 = (blockIdx.x % tiles_n) << 7;
  const int tid = threadIdx.x;
  const int w = tid >> 6, l = tid & 63;
  const int wr = w >> 1, wc = w & 1;
  const int lm = l & 15, lg = l >> 4;
  f32x4 acc[4][4] = {};

  const u16* Ab = A + (size_t)(m0 + w * 32 + (l >> 2)) * K + (l & 3) * 8;
  const u16* Bb = Bt + (size_t)(n0 + w * 32 + (l >> 2)) * K + (l & 3) * 8;
  u16* Albase = &Alds[w * 32 * 32];
  u16* Blbase = &Blds[w * 32 * 32];
  const size_t k16 = (size_t)16 * K;

  for (int k0 = 0; k0 < K; k0 += 32) {
    GLDS16(Ab + k0, Albase);
    GLDS16(Ab + k0 + k16, Albase + 16 * 32);
    GLDS16(Bb + k0, Blbase);
    GLDS16(Bb + k0 + k16, Blbase + 16 * 32);
    __syncthreads();
    bf16x8 af[4], bfr[4];
#pragma unroll
    for (int i = 0; i < 4; ++i) {
      af[i] = *(const bf16x8*)&Alds[(wr * 64 + i * 16 + lm) * 32 + lg * 8];
      bfr[i] = *(const bf16x8*)&Blds[(wc * 64 + i * 16 + lm) * 32 + lg * 8];
    }
#pragma unroll
    for (int i = 0; i < 4; ++i)
#pragma unroll
      for (int j = 0; j < 4; ++j)
        acc[i][j] = __builtin_amdgcn_mfma_f32_16x16x32_bf16(af[i], bfr[j], acc[i][j], 0, 0, 0);
    __syncthreads();
  }

#pragma unroll
  for (int i = 0; i < 4; ++i) {
#pragma unroll
    for (int r = 0; r < 4; ++r) {
      const int m = m0 + wr * 64 + i * 16 + lg * 4 + r;
      if constexpr (EPI == EPI_HEAD) {
        const int b = m / Rb, s = m - b * Rb;
        u16* o = (u16*)out;
#pragma unroll
        for (int j = 0; j < 4; ++j) {
          const int n = n0 + wc * 64 + j * 16 + lm;
          const int h = n >> 6, hd = n & 63;
          o[((size_t)((b * 16 + h) * Rb + s)) * 64 + hd] = f2bf(acc[i][j][r]);
        }
      } else if constexpr (EPI == EPI_RESID) {
        float* o = (float*)out;
#pragma unroll
        for (int j = 0; j < 4; ++j) {
          const int n = n0 + wc * 64 + j * 16 + lm;
          o[(size_t)m * N + n] = acc[i][j][r] + resid[(size_t)m * N + n];
        }
      } else {
        u16* o = (u16*)out;
#pragma unroll
        for (int j = 0; j < 4; ++j) {
          const int n = n0 + wc * 64 + j * 16 + lm;
          const float x = acc[i][j][r];
          const float c = x + 0.044715f * x * x * x;
          o[(size_t)m * N + n] = f2bf(0.5f * x * (1.f + tanhf(0.7978845608028654f * c)));
        }
      }
    }
  }
}

// ---------------------------------------------------------------- fused attention
// one WG (4 waves) per (b,h); wave w owns q-rows w*16..+16; online softmax over S.
__global__ __launch_bounds__(256) void attn_kernel(
    const u16* __restrict__ qh, const u16* __restrict__ kh,
    const u16* __restrict__ vt, const float* __restrict__ bias,
    u16* __restrict__ out, int S)
{
  const int bh = blockIdx.x, b = bh >> 4, h = bh & 15;
  const u16* Q = qh + (size_t)bh * 64 * 64;
  const u16* Kp = kh + (size_t)bh * S * 64;
  const u16* Vt = vt + (size_t)bh * 64 * S;
  __shared__ u16 Qlds[64 * 64];
  __shared__ u16 Klds[64 * 64];
  __shared__ u16 Vlds[64 * 64];
  __shared__ u16 Plds[4][16 * 64];
  const int tid = threadIdx.x, w = tid >> 6, l = tid & 63;
  const int lm = l & 15, lg = l >> 4;
  const int rr = l >> 3, cc = l & 7;   // staging: row-in-8, chunk position

  // stage Q (swizzled: LDS chunk p holds logical chunk p^(row&7); pre-swizzle global src)
#pragma unroll
  for (int i = 0; i < 2; ++i) {
    const int row = w * 16 + i * 8 + rr;
    GLDS16(Q + row * 64 + ((cc ^ (row & 7)) * 8), &Qlds[(w * 16 + i * 8) * 64]);
  }
  __syncthreads();
  bf16x8 aq[2];
  {
    const int row = w * 16 + lm;
#pragma unroll
    for (int kk = 0; kk < 2; ++kk)
      aq[kk] = *(const bf16x8*)&Qlds[row * 64 + (((kk * 4 + lg) ^ (row & 7)) * 8)];
  }

  float mrow[4], lrow[4];
  f32x4 oacc[4] = {};
#pragma unroll
  for (int r = 0; r < 4; ++r) { mrow[r] = -1e30f; lrow[r] = 0.f; }

  const int nt = S >> 6;
  for (int t = 0; t < nt; ++t) {
    const int s0 = t << 6;
    __syncthreads();
#pragma unroll
    for (int i = 0; i < 2; ++i) {
      const int row = w * 16 + i * 8 + rr;
      GLDS16(Kp + (size_t)(s0 + row) * 64 + ((cc ^ (row & 7)) * 8), &Klds[(w * 16 + i * 8) * 64]);
      GLDS16(Vt + (size_t)row * S + s0 + ((cc ^ (row & 7)) * 8), &Vlds[(w * 16 + i * 8) * 64]);
    }
    __syncthreads();

    f32x4 sacc[4] = {};
#pragma unroll
    for (int nf = 0; nf < 4; ++nf) {
      const int row = nf * 16 + lm;
#pragma unroll
      for (int kk = 0; kk < 2; ++kk) {
        const bf16x8 bk = *(const bf16x8*)&Klds[row * 64 + (((kk * 4 + lg) ^ (row & 7)) * 8)];
        sacc[nf] = __builtin_amdgcn_mfma_f32_16x16x32_bf16(aq[kk], bk, sacc[nf], 0, 0, 0);
      }
    }
    if (bias) {
#pragma unroll
      for (int nf = 0; nf < 4; ++nf) {
        const float bv = bias[(size_t)b * S + s0 + nf * 16 + lm];
#pragma unroll
        for (int r = 0; r < 4; ++r) sacc[nf][r] += bv;
      }
    }
    float corr[4];
#pragma unroll
    for (int r = 0; r < 4; ++r) {
      float mx = fmaxf(fmaxf(sacc[0][r], sacc[1][r]), fmaxf(sacc[2][r], sacc[3][r]));
      mx = fmaxf(mx, __shfl_xor(mx, 1)); mx = fmaxf(mx, __shfl_xor(mx, 2));
      mx = fmaxf(mx, __shfl_xor(mx, 4)); mx = fmaxf(mx, __shfl_xor(mx, 8));
      const float mnew = fmaxf(mrow[r], mx);
      corr[r] = __expf(mrow[r] - mnew);
      mrow[r] = mnew;
      float ps = 0.f;
#pragma unroll
      for (int nf = 0; nf < 4; ++nf) {
        const float p = __expf(sacc[nf][r] - mnew);
        sacc[nf][r] = p;
        ps += p;
      }
      ps += __shfl_xor(ps, 1); ps += __shfl_xor(ps, 2);
      ps += __shfl_xor(ps, 4); ps += __shfl_xor(ps, 8);
      lrow[r] = lrow[r] * corr[r] + ps;
    }
#pragma unroll
    for (int nf = 0; nf < 4; ++nf)
#pragma unroll
      for (int r = 0; r < 4; ++r) oacc[nf][r] *= corr[r];
    // P -> LDS (same swizzle, per-wave private region)
#pragma unroll
    for (int nf = 0; nf < 4; ++nf)
#pragma unroll
      for (int r = 0; r < 4; ++r) {
        const int q = lg * 4 + r;
        const int s = nf * 16 + lm;
        Plds[w][q * 64 + (((s >> 3) ^ (q & 7)) * 8) + (s & 7)] = f2bf(sacc[nf][r]);
      }
    bf16x8 pa[2];
#pragma unroll
    for (int kk = 0; kk < 2; ++kk)
      pa[kk] = *(const bf16x8*)&Plds[w][lm * 64 + (((kk * 4 + lg) ^ (lm & 7)) * 8)];
#pragma unroll
    for (int nf = 0; nf < 4; ++nf) {
      const int row = nf * 16 + lm;
#pragma unroll
      for (int kk = 0; kk < 2; ++kk) {
        const bf16x8 bv = *(const bf16x8*)&Vlds[row * 64 + (((kk * 4 + lg) ^ (row & 7)) * 8)];
        oacc[nf] = __builtin_amdgcn_mfma_f32_16x16x32_bf16(pa[kk], bv, oacc[nf], 0, 0, 0);
      }
    }
  }
#pragma unroll
  for (int r = 0; r < 4; ++r) {
    const float inv = 1.f / lrow[r];
    const int q = w * 16 + lg * 4 + r;
    u16* o = out + (size_t)(b * 64 + q) * 1024 + h * 64;
#pragma unroll
    for (int nf = 0; nf < 4; ++nf)
      o[nf * 16 + lm] = f2bf(oacc[nf][r] * inv);
  }
}

// ---------------------------------------------------------------- launch
extern "C" void kernel_launch(void* const* d_in, const int* in_sizes, int n_in,
                              void* d_out, int out_size, void* d_ws, size_t ws_size,
                              hipStream_t stream)
{
  (void)in_sizes; (void)n_in; (void)out_size; (void)ws_size;
  const float* embed      = (const float*)d_in[0];
  const int*   mask       = (const int*)d_in[1];
  const float* latents    = (const float*)d_in[2];
  const float* ctx_scale  = (const float*)d_in[3];
  const float* perc_scale = (const float*)d_in[4];
  const float* pre_attn   = (const float*)d_in[5];
  const float* wq         = (const float*)d_in[6];
  const float* wk         = (const float*)d_in[7];
  const float* wv         = (const float*)d_in[8];
  const float* wo         = (const float*)d_in[9];
  const float* qn         = (const float*)d_in[10];
  const float* kn         = (const float*)d_in[11];
  const float* pre_mlp    = (const float*)d_in[12];
  const float* wi         = (const float*)d_in[13];
  const float* wom        = (const float*)d_in[14];

  char* p = (char*)d_ws;
  auto alloc = [&](size_t bytes) { char* r = p; p += (bytes + 255) & ~(size_t)255; return r; };
  u16* ctx_bf  = (u16*)alloc(18874368ull * 2);   // [B][S][D] bf16
  u16* k_bf    = (u16*)alloc(18874368ull * 2);   // [B][H][Rb][64]
  u16* v_bf    = (u16*)alloc(18874368ull * 2);
  u16* vt_bf   = (u16*)alloc(18874368ull * 2);   // [B][H][64][Rb]
  u16* q_bf    = (u16*)alloc(2097152ull * 2);    // [B][H][64][64]
  u16* xin_bf  = (u16*)alloc(2097152ull * 2);
  u16* xmlp_bf = (u16*)alloc(2097152ull * 2);
  u16* attn_bf = (u16*)alloc(2097152ull * 2);
  u16* h_bf    = (u16*)alloc(8388608ull * 2);    // [2048][4096]
  float* lat   = (float*)alloc(2097152ull * 4);
  float* xbuf  = (float*)alloc(2097152ull * 4);
  float* bias  = (float*)alloc(18432ull * 4);
  u16* wqT  = (u16*)alloc(1048576ull * 2);
  u16* wkT  = (u16*)alloc(1048576ull * 2);
  u16* wvT  = (u16*)alloc(1048576ull * 2);
  u16* woT  = (u16*)alloc(1048576ull * 2);
  u16* wiT  = (u16*)alloc(4194304ull * 2);
  u16* womT = (u16*)alloc(4194304ull * 2);

  rmsnorm1024<0><<<18432, 256, 0, stream>>>(embed, ctx_scale, ctx_bf);
  lat_init<<<2048, 256, 0, stream>>>(latents, lat);
  bias_init<<<72, 256, 0, stream>>>(mask, bias, 18432);

  for (int l = 0; l < 8; ++l) {
    const bool cross = (l & 1) == 0;            // XATTN = 0,2,4,6
    const int Rb = cross ? 576 : 64;
    const int Mk = cross ? 18432 : 2048;
    transpose_weights<<<3072, 256, 0, stream>>>(
        wq + (size_t)l * 1048576, wk + (size_t)l * 1048576, wv + (size_t)l * 1048576,
        wo + (size_t)l * 1048576, wi + (size_t)l * 4194304, wom + (size_t)l * 4194304,
        wqT, wkT, wvT, woT, wiT, womT);
    rmsnorm1024<0><<<2048, 256, 0, stream>>>(lat, pre_attn + l * 1024, xin_bf);
    gemm_bf16<EPI_HEAD><<<128, 256, 0, stream>>>(xin_bf, wqT, q_bf, nullptr, 2048, 1024, 1024, 64);
    const u16* kvsrc = cross ? ctx_bf : xin_bf;
    gemm_bf16<EPI_HEAD><<<Mk / 128 * 8, 256, 0, stream>>>(kvsrc, wkT, k_bf, nullptr, Mk, 1024, 1024, Rb);
    gemm_bf16<EPI_HEAD><<<Mk / 128 * 8, 256, 0, stream>>>(kvsrc, wvT, v_bf, nullptr, Mk, 1024, 1024, Rb);
    qknorm2<<<2048 + Mk, 256, 0, stream>>>(q_bf, qn + l * 64, k_bf, kn + l * 64, 32768);
    vtrans<<<512 * (Rb / 64), 256, 0, stream>>>(v_bf, vt_bf, Rb);
    attn_kernel<<<512, 256, 0, stream>>>(q_bf, k_bf, vt_bf, cross ? bias : nullptr, attn_bf, Rb);
    gemm_bf16<EPI_RESID><<<128, 256, 0, stream>>>(attn_bf, woT, xbuf, lat, 2048, 1024, 1024, 0);
    rmsnorm1024<0><<<2048, 256, 0, stream>>>(xbuf, pre_mlp + l * 1024, xmlp_bf);
    gemm_bf16<EPI_GELU><<<512, 256, 0, stream>>>(xmlp_bf, wiT, h_bf, nullptr, 2048, 4096, 1024, 0);
    gemm_bf16<EPI_RESID><<<128, 256, 0, stream>>>(h_bf, womT, lat, xbuf, 2048, 1024, 4096, 0);
  }
  rmsnorm1024<1><<<2048, 256, 0, stream>>>(lat, perc_scale, d_out);
}